// Round 2
// baseline (433.423 us; speedup 1.0000x reference)
//
#include <hip/hip_runtime.h>
#include <hip/hip_bf16.h>
#include <stdint.h>

#define NTOK 16384
#define DDIM 4096
#define NEXP 128
#define BM 32
#define BK 64
#define BKP 72  // padded A row stride in bf16 elems (144 B): breaks pow2 bank stride, keeps 16B align

typedef __attribute__((ext_vector_type(8))) short short8;   // 8 bf16 = 4 VGPRs (MFMA A/B frag)
typedef __attribute__((ext_vector_type(4))) float f32x4;    // MFMA C/D frag

// fp32 -> (hi, lo) bf16 pair, both RNE. f ~= hi + lo, |err| <~ 2^-17 |f|.
__device__ __forceinline__ void split_bf16(float f, uint32_t& h, uint32_t& l) {
    uint32_t u = __float_as_uint(f);
    h = (u + 0x7FFFu + ((u >> 16) & 1u)) >> 16;
    float r = f - __uint_as_float(h << 16);
    uint32_t v = __float_as_uint(r);
    l = (v + 0x7FFFu + ((v >> 16) & 1u)) >> 16;
}

// async global->LDS, 16 B per lane; LDS dest is wave-uniform base + lane*16
__device__ __forceinline__ void gld_lds16(const void* g, void* l) {
    __builtin_amdgcn_global_load_lds(
        (const __attribute__((address_space(1))) void*)g,
        (__attribute__((address_space(3))) void*)l, 16, 0, 0);
}

// ---- kernel 1: split wg_weight [128][4096] fp32 -> w_hi, w_lo bf16 in ws ----
__global__ void prep_w(const float* __restrict__ w,
                       uint16_t* __restrict__ whi, uint16_t* __restrict__ wlo) {
    int i = (blockIdx.x * blockDim.x + threadIdx.x) * 4;
    float4 f = *(const float4*)(w + i);
    uint32_t h0, h1, h2, h3, l0, l1, l2, l3;
    split_bf16(f.x, h0, l0);
    split_bf16(f.y, h1, l1);
    split_bf16(f.z, h2, l2);
    split_bf16(f.w, h3, l3);
    *(uint2*)(whi + i) = make_uint2(h0 | (h1 << 16), h2 | (h3 << 16));
    *(uint2*)(wlo + i) = make_uint2(l0 | (l1 << 16), l2 | (l3 << 16));
}

// ---- kernel 2: fused logits GEMM (split-bf16 3-MFMA) + softmax + adaptive top-k ----
// 512 blocks x 256 thr; each block: 32 tokens x 128 experts; 4 waves each own 32x32.
__global__ __launch_bounds__(256, 2) void gate_fused(
    const float* __restrict__ x,
    const uint16_t* __restrict__ whi, const uint16_t* __restrict__ wlo,
    const float* __restrict__ mask,
    float* __restrict__ S, float* __restrict__ topk_out)
{
    __shared__ uint16_t sAh[BM * BKP], sAl[BM * BKP];       // 4.6 KB each, padded
    __shared__ uint16_t sBh[NEXP * BK], sBl[NEXP * BK];     // 16 KB each, linear+swizzled
    __shared__ float    L[BM][NEXP];                        // 16 KB logit tile

    const int tid  = threadIdx.x;
    const int lane = tid & 63;
    const int wave = tid >> 6;
    const int m0   = blockIdx.x * BM;

    // mask -> regs (used in tail)
    const float mk0 = mask[lane];
    const float mk1 = mask[lane + 64];

    // A staging ids: thread t -> row am = t>>3, 8-elem k-chunk akc = t&7
    const int am  = tid >> 3;
    const int akc = tid & 7;
    const float* xp = x + (size_t)(m0 + am) * DDIM + akc * 8;

    // preload first A tile
    float4 fa = *(const float4*)(xp);
    float4 fb = *(const float4*)(xp + 4);

    f32x4 acc[2][2];
    #pragma unroll
    for (int mt = 0; mt < 2; ++mt)
        #pragma unroll
        for (int nt = 0; nt < 2; ++nt)
            acc[mt][nt] = (f32x4){0.f, 0.f, 0.f, 0.f};

    const int q = lane >> 4;   // quad id (k-group selector)
    const int c = lane & 15;   // row (A) / col (B) within 16

    // B async-copy per-lane global swizzle ids (per wave, 4 instrs x 64 lanes cover 1024 chunks)
    int bn[4], bkc[4];
    #pragma unroll
    for (int j = 0; j < 4; ++j) {
        const int p = (wave * 4 + j) * 64 + lane;   // LDS chunk this lane fills
        bn[j]  = p >> 3;                            // expert row
        bkc[j] = (p & 7) ^ (bn[j] & 7);             // swizzled k-chunk
    }

    for (int k0 = 0; k0 < DDIM; k0 += BK) {
        // ---- stage A: split fp32 -> bf16 hi/lo -> padded LDS ----
        uint32_t h[8], l[8];
        split_bf16(fa.x, h[0], l[0]); split_bf16(fa.y, h[1], l[1]);
        split_bf16(fa.z, h[2], l[2]); split_bf16(fa.w, h[3], l[3]);
        split_bf16(fb.x, h[4], l[4]); split_bf16(fb.y, h[5], l[5]);
        split_bf16(fb.z, h[6], l[6]); split_bf16(fb.w, h[7], l[7]);
        *(uint4*)&sAh[am * BKP + akc * 8] =
            make_uint4(h[0] | (h[1] << 16), h[2] | (h[3] << 16),
                       h[4] | (h[5] << 16), h[6] | (h[7] << 16));
        *(uint4*)&sAl[am * BKP + akc * 8] =
            make_uint4(l[0] | (l[1] << 16), l[2] | (l[3] << 16),
                       l[4] | (l[5] << 16), l[6] | (l[7] << 16));

        // ---- stage B: async global->LDS, source-address swizzled ----
        #pragma unroll
        for (int j = 0; j < 4; ++j) {
            const size_t go = (size_t)bn[j] * DDIM + k0 + bkc[j] * 8;
            const int lb = (wave * 4 + j) * 512;    // uniform LDS elem base (1 KB per instr)
            gld_lds16(whi + go, sBh + lb);
            gld_lds16(wlo + go, sBl + lb);
        }
        __syncthreads();   // drains ds_writes + global_load_lds (vmcnt+lgkmcnt)

        // ---- prefetch next A tile (overlaps MFMA block) ----
        {
            const int kn = (k0 + BK < DDIM) ? (k0 + BK) : 0;  // last iter: dummy reload
            fa = *(const float4*)(xp + kn);
            fb = *(const float4*)(xp + kn + 4);
        }

        // ---- compute: 2 k-steps of 32, 2x2 tiles, 3 MFMAs each ----
        #pragma unroll
        for (int ks = 0; ks < 2; ++ks) {
            const int kb  = ks * 32 + q * 8;  // A elem offset in row
            const int kb8 = ks * 4 + q;       // B k-chunk index
            short8 ah[2], alo[2], bh[2], blo[2];
            #pragma unroll
            for (int mt = 0; mt < 2; ++mt) {
                const int ro = (mt * 16 + c) * BKP + kb;
                ah[mt]  = *(const short8*)&sAh[ro];
                alo[mt] = *(const short8*)&sAl[ro];
            }
            #pragma unroll
            for (int nt = 0; nt < 2; ++nt) {
                const int ne = wave * 32 + nt * 16 + c;              // expert row
                const int ch = ne * 8 + (kb8 ^ (ne & 7));            // swizzled chunk
                bh[nt]  = *(const short8*)&sBh[ch * 8];
                blo[nt] = *(const short8*)&sBl[ch * 8];
            }
            #pragma unroll
            for (int mt = 0; mt < 2; ++mt)
                #pragma unroll
                for (int nt = 0; nt < 2; ++nt) {
                    acc[mt][nt] = __builtin_amdgcn_mfma_f32_16x16x32_bf16(alo[mt], bh[nt],  acc[mt][nt], 0, 0, 0);
                    acc[mt][nt] = __builtin_amdgcn_mfma_f32_16x16x32_bf16(ah[mt],  blo[nt], acc[mt][nt], 0, 0, 0);
                    acc[mt][nt] = __builtin_amdgcn_mfma_f32_16x16x32_bf16(ah[mt],  bh[nt],  acc[mt][nt], 0, 0, 0);
                }
        }
        __syncthreads();
    }

    // ---- epilogue: accs -> LDS logit tile (C/D layout: col=lane&15, row=(lane>>4)*4+reg) ----
    #pragma unroll
    for (int mt = 0; mt < 2; ++mt)
        #pragma unroll
        for (int nt = 0; nt < 2; ++nt) {
            const int e = wave * 32 + nt * 16 + c;
            #pragma unroll
            for (int r = 0; r < 4; ++r)
                L[mt * 16 + q * 4 + r][e] = acc[mt][nt][r];
        }
    __syncthreads();

    // ---- fused postproc: each wave handles 8 tokens ----
    const bool a0 = (mk0 != 0.f), a1 = (mk1 != 0.f);
    const int active = __popcll(__ballot(a0)) + __popcll(__ballot(a1));

    for (int i = 0; i < 8; ++i) {
        const int lt  = wave * 8 + i;
        const int tok = m0 + lt;
        float s0 = L[lt][lane], s1 = L[lt][lane + 64];

        float mx = fmaxf(a0 ? s0 : -3.0e38f, a1 ? s1 : -3.0e38f);
        #pragma unroll
        for (int off = 32; off; off >>= 1) mx = fmaxf(mx, __shfl_xor(mx, off));

        float p0 = a0 ? __expf(s0 - mx) : 0.f;
        float p1 = a1 ? __expf(s1 - mx) : 0.f;
        float sum = p0 + p1;
        #pragma unroll
        for (int off = 32; off; off >>= 1) sum += __shfl_xor(sum, off);

        const float inv = 1.0f / sum;
        const float sc0 = p0 * inv + 1e-14f;
        const float sc1 = p1 * inv + 1e-14f;
        S[(size_t)tok * NEXP + lane]      = sc0;
        S[(size_t)tok * NEXP + lane + 64] = sc1;

        // adaptive top-k: extract maxima until cum >= 0.5 (matches sorted-cumsum order)
        float v0 = sc0, v1 = sc1;
        float cum = 0.f;
        int k = 0;
        while (cum < 0.5f && k < NEXP) {
            float mv = fmaxf(v0, v1);
            #pragma unroll
            for (int off = 32; off; off >>= 1) mv = fmaxf(mv, __shfl_xor(mv, off));
            cum += mv;
            ++k;
            unsigned long long b = __ballot(v0 == mv || v1 == mv);
            int first = __ffsll(b) - 1;
            if (lane == first) {
                if (v0 == mv) v0 = -1.f; else v1 = -1.f;
            }
        }
        int topk = k < active ? k : active;
        if (lane == 0) topk_out[tok] = (float)topk;
    }
}

extern "C" void kernel_launch(void* const* d_in, const int* in_sizes, int n_in,
                              void* d_out, int out_size, void* d_ws, size_t ws_size,
                              hipStream_t stream) {
    (void)in_sizes; (void)n_in; (void)out_size; (void)ws_size;
    const float* x    = (const float*)d_in[0];
    const float* w    = (const float*)d_in[1];
    const float* mask = (const float*)d_in[2];

    float* S    = (float*)d_out;                  // [16384,128] scores
    float* topk = S + (size_t)NTOK * NEXP;        // [16384] top_k as float

    uint16_t* whi = (uint16_t*)d_ws;              // [128,4096] bf16 hi
    uint16_t* wlo = whi + (size_t)NEXP * DDIM;    // [128,4096] bf16 lo

    hipLaunchKernelGGL(prep_w, dim3((NEXP * DDIM) / (256 * 4)), dim3(256), 0, stream,
                       w, whi, wlo);
    hipLaunchKernelGGL(gate_fused, dim3(NTOK / BM), dim3(256), 0, stream,
                       x, whi, wlo, mask, S, topk);
}